// Round 1
// baseline (261.373 us; speedup 1.0000x reference)
//
#include <hip/hip_runtime.h>
#include <hip/hip_bf16.h>

#define H_ 8
#define D_ 64
#define IN_ 512
#define B_ 4
#define N_ 2048
#define TOK_ (B_*N_)
#define SCALE_ 0.125f

typedef __attribute__((ext_vector_type(8))) short short8;
typedef __attribute__((ext_vector_type(4))) float f32x4;

__device__ __forceinline__ unsigned short f2bf(float f) {
  unsigned int u = __float_as_uint(f);
  u += 0x7FFFu + ((u >> 16) & 1u);
  return (unsigned short)(u >> 16);
}

__device__ __forceinline__ short8 cvt8(const float4 a, const float4 b) {
  short8 r;
  r[0]=(short)f2bf(a.x); r[1]=(short)f2bf(a.y); r[2]=(short)f2bf(a.z); r[3]=(short)f2bf(a.w);
  r[4]=(short)f2bf(b.x); r[5]=(short)f2bf(b.y); r[6]=(short)f2bf(b.z); r[7]=(short)f2bf(b.w);
  return r;
}

// ---------------------------------------------------------------------------
// Kernel 1: fused QKV projection.  y = x @ W^T, virtual N = 1536 (Wq | Wkv).
// Block tile: 128 tokens x 64 out-cols, K-step 32. 4 waves, each 32x64.
// Writes bf16: Q,K -> [b,h,n,d]; V -> [b,h,d,n] (transposed for PV B-operand).
// ---------------------------------------------------------------------------
__global__ __launch_bounds__(256) void qkv_proj_kernel(
    const float* __restrict__ x, const float* __restrict__ Wq,
    const float* __restrict__ Wkv,
    unsigned short* __restrict__ qws, unsigned short* __restrict__ kws,
    unsigned short* __restrict__ vws)
{
  __shared__ __attribute__((aligned(16))) unsigned short As[128][40]; // pad: 80B rows
  __shared__ __attribute__((aligned(16))) unsigned short Bs[64][40];

  const int t0 = blockIdx.x * 128;
  const int c0 = blockIdx.y * 64;                 // 0..1535 (global out col)
  const float* Wbase = (c0 < 512) ? (Wq + (size_t)c0 * IN_)
                                  : (Wkv + (size_t)(c0 - 512) * IN_);
  const int cls = (c0 < 512) ? 0 : ((c0 < 1024) ? 1 : 2);  // 0=q 1=k 2=v

  const int tid  = threadIdx.x;
  const int wave = tid >> 6, lane = tid & 63;
  const int quad = lane >> 4, l16 = lane & 15;

  const int ar = tid >> 1, ac = (tid & 1) * 16;   // A stage: 16 floats/thread
  const int br = tid >> 2, bc = (tid & 3) * 8;    // B stage: 8 floats/thread

  f32x4 zero4 = {0.f, 0.f, 0.f, 0.f};
  f32x4 acc[2][4];
  #pragma unroll
  for (int i = 0; i < 2; i++)
    #pragma unroll
    for (int j = 0; j < 4; j++) acc[i][j] = zero4;

  for (int k0 = 0; k0 < IN_; k0 += 32) {
    __syncthreads();
    const float4* xp = (const float4*)(x + (size_t)(t0 + ar) * IN_ + k0 + ac);
    float4 a0 = xp[0], a1 = xp[1], a2 = xp[2], a3 = xp[3];
    const float4* wp = (const float4*)(Wbase + (size_t)br * IN_ + k0 + bc);
    float4 b0 = wp[0], b1 = wp[1];
    *(short8*)&As[ar][ac]     = cvt8(a0, a1);
    *(short8*)&As[ar][ac + 8] = cvt8(a2, a3);
    *(short8*)&Bs[br][bc]     = cvt8(b0, b1);
    __syncthreads();

    short8 af0 = *(const short8*)&As[wave * 32 + l16][quad * 8];
    short8 af1 = *(const short8*)&As[wave * 32 + 16 + l16][quad * 8];
    #pragma unroll
    for (int nb = 0; nb < 4; nb++) {
      short8 bf = *(const short8*)&Bs[nb * 16 + l16][quad * 8];
      acc[0][nb] = __builtin_amdgcn_mfma_f32_16x16x32_bf16(af0, bf, acc[0][nb], 0, 0, 0);
      acc[1][nb] = __builtin_amdgcn_mfma_f32_16x16x32_bf16(af1, bf, acc[1][nb], 0, 0, 0);
    }
  }

  // Epilogue: C/D layout col = l16, row = quad*4 + reg
  #pragma unroll
  for (int mb = 0; mb < 2; mb++) {
    const int trow = t0 + wave * 32 + mb * 16 + quad * 4;  // +reg
    const int bb = trow >> 11, nn = trow & (N_ - 1);       // 4 regs: nn..nn+3
    #pragma unroll
    for (int nb = 0; nb < 4; nb++) {
      const int c = (c0 & 511) + nb * 16 + l16;
      const int hh = c >> 6, dd = c & 63;
      if (cls == 2) {
        ushort4 pk;
        pk.x = f2bf(acc[mb][nb][0]); pk.y = f2bf(acc[mb][nb][1]);
        pk.z = f2bf(acc[mb][nb][2]); pk.w = f2bf(acc[mb][nb][3]);
        *(ushort4*)(vws + ((size_t)(bb * H_ + hh) * D_ + dd) * N_ + nn) = pk;
      } else {
        unsigned short* dst = (cls == 0) ? qws : kws;
        size_t base = ((size_t)(bb * H_ + hh) * N_ + nn) * D_ + dd;
        dst[base]          = f2bf(acc[mb][nb][0]);
        dst[base + D_]     = f2bf(acc[mb][nb][1]);
        dst[base + 2 * D_] = f2bf(acc[mb][nb][2]);
        dst[base + 3 * D_] = f2bf(acc[mb][nb][3]);
      }
    }
  }
}

// ---------------------------------------------------------------------------
// Kernel 2: flash attention. Block = (qtile 128 rows) x (one b,h).
// Q frags hoisted to registers; K tile [64][64], V^T tile [64 d][64 m] in LDS;
// P round-trips through LDS (C-layout -> A-layout). Online softmax per row,
// row stats wave-local (row = quad*4+reg), butterfly over 16 lanes.
// ---------------------------------------------------------------------------
__global__ __launch_bounds__(256) void attention_kernel(
    const unsigned short* __restrict__ qws,
    const unsigned short* __restrict__ kws,
    const unsigned short* __restrict__ vws,
    unsigned short* __restrict__ ows)
{
  __shared__ __attribute__((aligned(16))) unsigned short Ks[64][72];   // 144B rows
  __shared__ __attribute__((aligned(16))) unsigned short Vs[64][72];   // [d][m']
  __shared__ __attribute__((aligned(16))) unsigned short Ps[128][72];  // Q then P

  const int qt = blockIdx.x;            // 0..15
  const int bh = blockIdx.y;            // 0..31
  const int q0 = qt * 128;
  const int tid  = threadIdx.x;
  const int wave = tid >> 6, lane = tid & 63;
  const int quad = lane >> 4, l16 = lane & 15;

  const unsigned short* qbase = qws + (size_t)bh * N_ * D_;
  const unsigned short* kbase = kws + (size_t)bh * N_ * D_;
  const unsigned short* vbase = vws + (size_t)bh * D_ * N_;

  // --- stage Q tile (128x64) into Ps ---
  {
    const int r = tid >> 3;             // 0..31
    const int c = (tid & 7) * 8;        // 0..56
    #pragma unroll
    for (int p = 0; p < 4; p++) {
      const int row = r + p * 32;
      uint4 v = *(const uint4*)(qbase + (size_t)(q0 + row) * D_ + c);
      *(uint4*)&Ps[row][c] = v;
    }
  }
  __syncthreads();
  short8 qf[2][2];
  #pragma unroll
  for (int mb = 0; mb < 2; mb++)
    #pragma unroll
    for (int kc = 0; kc < 2; kc++)
      qf[mb][kc] = *(const short8*)&Ps[wave * 32 + mb * 16 + l16][kc * 32 + quad * 8];

  f32x4 zero4 = {0.f, 0.f, 0.f, 0.f};
  f32x4 o[2][4];
  float mi[2][4], li[2][4];
  #pragma unroll
  for (int mb = 0; mb < 2; mb++) {
    #pragma unroll
    for (int db = 0; db < 4; db++) o[mb][db] = zero4;
    #pragma unroll
    for (int r = 0; r < 4; r++) { mi[mb][r] = -1e30f; li[mb][r] = 0.f; }
  }

  const int sr = tid >> 2;              // 0..63
  const int sc = (tid & 3) * 16;        // 0,16,32,48

  for (int kt = 0; kt < N_ / 64; kt++) {
    const int k0 = kt * 64;
    __syncthreads();   // prev PV reads done before restaging K/V (also guards Q->P reuse)
    {
      const uint4* kp = (const uint4*)(kbase + (size_t)(k0 + sr) * D_ + sc);
      uint4 kv0 = kp[0], kv1 = kp[1];
      const uint4* vp = (const uint4*)(vbase + (size_t)sr * N_ + k0 + sc);
      uint4 vv0 = vp[0], vv1 = vp[1];
      *(uint4*)&Ks[sr][sc]     = kv0;
      *(uint4*)&Ks[sr][sc + 8] = kv1;
      *(uint4*)&Vs[sr][sc]     = vv0;
      *(uint4*)&Vs[sr][sc + 8] = vv1;
    }
    __syncthreads();

    // --- S = Q K^T (rows=queries, cols=keys) ---
    f32x4 s[2][4];
    #pragma unroll
    for (int mb = 0; mb < 2; mb++)
      #pragma unroll
      for (int nb = 0; nb < 4; nb++) s[mb][nb] = zero4;
    #pragma unroll
    for (int kc = 0; kc < 2; kc++) {
      short8 kf[4];
      #pragma unroll
      for (int nb = 0; nb < 4; nb++)
        kf[nb] = *(const short8*)&Ks[nb * 16 + l16][kc * 32 + quad * 8];
      #pragma unroll
      for (int mb = 0; mb < 2; mb++)
        #pragma unroll
        for (int nb = 0; nb < 4; nb++)
          s[mb][nb] = __builtin_amdgcn_mfma_f32_16x16x32_bf16(qf[mb][kc], kf[nb], s[mb][nb], 0, 0, 0);
    }

    // --- online softmax ---
    #pragma unroll
    for (int mb = 0; mb < 2; mb++) {
      float rmax[4];
      #pragma unroll
      for (int r = 0; r < 4; r++)
        rmax[r] = fmaxf(fmaxf(s[mb][0][r], s[mb][1][r]), fmaxf(s[mb][2][r], s[mb][3][r]));
      #pragma unroll
      for (int mask = 1; mask < 16; mask <<= 1)
        #pragma unroll
        for (int r = 0; r < 4; r++)
          rmax[r] = fmaxf(rmax[r], __shfl_xor(rmax[r], mask, 16));

      float alpha[4];
      #pragma unroll
      for (int r = 0; r < 4; r++) {
        float mnew = fmaxf(mi[mb][r], rmax[r] * SCALE_);
        alpha[r] = __expf(mi[mb][r] - mnew);
        mi[mb][r] = mnew;
      }
      float rsum[4] = {0.f, 0.f, 0.f, 0.f};
      #pragma unroll
      for (int nb = 0; nb < 4; nb++)
        #pragma unroll
        for (int r = 0; r < 4; r++) {
          float p = __expf(s[mb][nb][r] * SCALE_ - mi[mb][r]);
          s[mb][nb][r] = p;
          rsum[r] += p;
        }
      #pragma unroll
      for (int mask = 1; mask < 16; mask <<= 1)
        #pragma unroll
        for (int r = 0; r < 4; r++)
          rsum[r] += __shfl_xor(rsum[r], mask, 16);
      #pragma unroll
      for (int r = 0; r < 4; r++)
        li[mb][r] = li[mb][r] * alpha[r] + rsum[r];
      #pragma unroll
      for (int db = 0; db < 4; db++)
        #pragma unroll
        for (int r = 0; r < 4; r++)
          o[mb][db][r] *= alpha[r];
      // write P (bf16) back to Ps in C-layout position
      const int prow = wave * 32 + mb * 16 + quad * 4;
      #pragma unroll
      for (int nb = 0; nb < 4; nb++)
        #pragma unroll
        for (int r = 0; r < 4; r++)
          Ps[prow + r][nb * 16 + l16] = f2bf(s[mb][nb][r]);
    }
    __syncthreads();   // P visible for A-operand reads

    // --- O += P @ V ---
    #pragma unroll
    for (int kc = 0; kc < 2; kc++) {
      short8 vf[4];
      #pragma unroll
      for (int db = 0; db < 4; db++)
        vf[db] = *(const short8*)&Vs[db * 16 + l16][kc * 32 + quad * 8];
      short8 pf[2];
      #pragma unroll
      for (int mb = 0; mb < 2; mb++)
        pf[mb] = *(const short8*)&Ps[wave * 32 + mb * 16 + l16][kc * 32 + quad * 8];
      #pragma unroll
      for (int mb = 0; mb < 2; mb++)
        #pragma unroll
        for (int db = 0; db < 4; db++)
          o[mb][db] = __builtin_amdgcn_mfma_f32_16x16x32_bf16(pf[mb], vf[db], o[mb][db], 0, 0, 0);
    }
  }

  // --- epilogue: O/l -> bf16 -> [b][n][h*64+d] ---
  const int b_ = bh >> 3, h_ = bh & 7;
  #pragma unroll
  for (int mb = 0; mb < 2; mb++) {
    float inv[4];
    #pragma unroll
    for (int r = 0; r < 4; r++) inv[r] = 1.f / li[mb][r];
    const int row0 = q0 + wave * 32 + mb * 16 + quad * 4;
    #pragma unroll
    for (int db = 0; db < 4; db++) {
      const int col = h_ * 64 + db * 16 + l16;
      #pragma unroll
      for (int r = 0; r < 4; r++)
        ows[((size_t)b_ * N_ + row0 + r) * (H_ * D_) + col] = f2bf(o[mb][db][r] * inv[r]);
    }
  }
}

// ---------------------------------------------------------------------------
// Kernel 3: output projection  y[t][i] = sum_o A[t][o] * Wo[i][o] + bo[i]
// ---------------------------------------------------------------------------
__global__ __launch_bounds__(256) void out_proj_kernel(
    const unsigned short* __restrict__ ain, const float* __restrict__ Wo,
    const float* __restrict__ bo, float* __restrict__ y)
{
  __shared__ __attribute__((aligned(16))) unsigned short As[128][40];
  __shared__ __attribute__((aligned(16))) unsigned short Bs[64][40];

  const int t0 = blockIdx.x * 128;
  const int c0 = blockIdx.y * 64;
  const int tid  = threadIdx.x;
  const int wave = tid >> 6, lane = tid & 63;
  const int quad = lane >> 4, l16 = lane & 15;
  const int ar = tid >> 1, ac = (tid & 1) * 16;
  const int br = tid >> 2, bc = (tid & 3) * 8;

  f32x4 zero4 = {0.f, 0.f, 0.f, 0.f};
  f32x4 acc[2][4];
  #pragma unroll
  for (int i = 0; i < 2; i++)
    #pragma unroll
    for (int j = 0; j < 4; j++) acc[i][j] = zero4;

  for (int k0 = 0; k0 < IN_; k0 += 32) {
    __syncthreads();
    const uint4* ap = (const uint4*)(ain + (size_t)(t0 + ar) * IN_ + k0 + ac);
    uint4 a0 = ap[0], a1 = ap[1];
    const float4* wp = (const float4*)(Wo + (size_t)(c0 + br) * IN_ + k0 + bc);
    float4 b0 = wp[0], b1 = wp[1];
    *(uint4*)&As[ar][ac]     = a0;
    *(uint4*)&As[ar][ac + 8] = a1;
    *(short8*)&Bs[br][bc]    = cvt8(b0, b1);
    __syncthreads();

    short8 af0 = *(const short8*)&As[wave * 32 + l16][quad * 8];
    short8 af1 = *(const short8*)&As[wave * 32 + 16 + l16][quad * 8];
    #pragma unroll
    for (int nb = 0; nb < 4; nb++) {
      short8 bf = *(const short8*)&Bs[nb * 16 + l16][quad * 8];
      acc[0][nb] = __builtin_amdgcn_mfma_f32_16x16x32_bf16(af0, bf, acc[0][nb], 0, 0, 0);
      acc[1][nb] = __builtin_amdgcn_mfma_f32_16x16x32_bf16(af1, bf, acc[1][nb], 0, 0, 0);
    }
  }

  #pragma unroll
  for (int mb = 0; mb < 2; mb++) {
    const int t = t0 + wave * 32 + mb * 16 + quad * 4;
    #pragma unroll
    for (int nb = 0; nb < 4; nb++) {
      const int c = c0 + nb * 16 + l16;
      const float bias = bo[c];
      float* dst = y + (size_t)t * IN_ + c;
      dst[0]        = acc[mb][nb][0] + bias;
      dst[IN_]      = acc[mb][nb][1] + bias;
      dst[2 * IN_]  = acc[mb][nb][2] + bias;
      dst[3 * IN_]  = acc[mb][nb][3] + bias;
    }
  }
}

extern "C" void kernel_launch(void* const* d_in, const int* in_sizes, int n_in,
                              void* d_out, int out_size, void* d_ws, size_t ws_size,
                              hipStream_t stream) {
  const float* x   = (const float*)d_in[0];
  const float* Wq  = (const float*)d_in[1];
  const float* Wkv = (const float*)d_in[2];
  const float* Wo  = (const float*)d_in[3];
  const float* bo  = (const float*)d_in[4];
  float* out = (float*)d_out;

  // workspace: 4 bf16 tensors of TOK*512 elements each (8 MB each, 32 MB total)
  unsigned short* qws = (unsigned short*)d_ws;
  unsigned short* kws = qws + (size_t)TOK_ * 512;
  unsigned short* vws = kws + (size_t)TOK_ * 512;
  unsigned short* ows = vws + (size_t)TOK_ * 512;

  qkv_proj_kernel<<<dim3(TOK_ / 128, 1536 / 64), 256, 0, stream>>>(x, Wq, Wkv, qws, kws, vws);
  attention_kernel<<<dim3(N_ / 128, B_ * H_), 256, 0, stream>>>(qws, kws, vws, ows);
  out_proj_kernel<<<dim3(TOK_ / 128, 512 / 64), 256, 0, stream>>>(ows, Wo, bo, out);
}

// Round 2
// 253.163 us; speedup vs baseline: 1.0324x; 1.0324x over previous
//
#include <hip/hip_runtime.h>
#include <hip/hip_bf16.h>

#define H_ 8
#define D_ 64
#define IN_ 512
#define B_ 4
#define N_ 2048
#define TOK_ (B_*N_)
// softmax in exp2 domain: scale * log2(e)
#define CLOG2_ 0.18033688011112042f

typedef __attribute__((ext_vector_type(8))) short short8;
typedef __attribute__((ext_vector_type(4))) short bs4;
typedef __attribute__((ext_vector_type(4))) float f32x4;

__device__ __forceinline__ unsigned short f2bf(float f) {
  unsigned int u = __float_as_uint(f);
  u += 0x7FFFu + ((u >> 16) & 1u);
  return (unsigned short)(u >> 16);
}

__device__ __forceinline__ short8 cvt8(const float4 a, const float4 b) {
  short8 r;
  r[0]=(short)f2bf(a.x); r[1]=(short)f2bf(a.y); r[2]=(short)f2bf(a.z); r[3]=(short)f2bf(a.w);
  r[4]=(short)f2bf(b.x); r[5]=(short)f2bf(b.y); r[6]=(short)f2bf(b.z); r[7]=(short)f2bf(b.w);
  return r;
}

// ---------------------------------------------------------------------------
// Kernel 0: convert x (fp32) -> bf16, stored in the ows region (free until
// attention writes it; qkv_gemm reads it first — stream-ordered).
// ---------------------------------------------------------------------------
__global__ __launch_bounds__(256) void conv_x_kernel(
    const float* __restrict__ x, unsigned short* __restrict__ xbf)
{
  size_t i = ((size_t)blockIdx.x * 256 + threadIdx.x) * 8;
  float4 a = *(const float4*)(x + i);
  float4 b = *(const float4*)(x + i + 4);
  *(short8*)(xbf + i) = cvt8(a, b);
}

// ---------------------------------------------------------------------------
// Kernel 1: QKV projection. C[8192][1536] = x_bf @ [Wq|Wkv]^T.
// 128x128 tile, BK=64, prefetched staging (A bf16, B fp32->bf16 at load).
// Q,K -> [b,h,n,d]; V -> [b,h,d,n] (transposed).
// ---------------------------------------------------------------------------
__global__ __launch_bounds__(256, 3) void qkv_gemm_kernel(
    const unsigned short* __restrict__ xbf, const float* __restrict__ Wq,
    const float* __restrict__ Wkv,
    unsigned short* __restrict__ qws, unsigned short* __restrict__ kws,
    unsigned short* __restrict__ vws)
{
  __shared__ __attribute__((aligned(16))) unsigned short As[128][72];
  __shared__ __attribute__((aligned(16))) unsigned short Bs[128][72];

  const int t0 = blockIdx.x * 128;
  const int c0 = blockIdx.y * 128;                 // 0..1535
  const int cls = c0 >> 9;                         // 0=q 1=k 2=v (uniform/block)
  const float* wbase = (cls == 0) ? Wq : Wkv;
  const int wrow0 = c0 - (cls ? 512 : 0);

  const int tid = threadIdx.x;
  const int wave = tid >> 6, lane = tid & 63;
  const int quad = lane >> 4, l16 = lane & 15;
  const int wm = wave >> 1, wn = wave & 1;

  const int sr = tid >> 1, sc = (tid & 1) * 32;    // staging: 2 thr/row, 32 elems

  uint4 aReg[4];
  short8 bReg[4];

  auto loadA = [&](int k0) {
    const uint4* p = (const uint4*)(xbf + (size_t)(t0 + sr) * IN_ + k0 + sc);
    aReg[0] = p[0]; aReg[1] = p[1]; aReg[2] = p[2]; aReg[3] = p[3];
  };
  auto loadB = [&](int k0) {
    const float4* p = (const float4*)(wbase + (size_t)(wrow0 + sr) * IN_ + k0 + sc);
    float4 b0 = p[0], b1 = p[1], b2 = p[2], b3 = p[3];
    float4 b4 = p[4], b5 = p[5], b6 = p[6], b7 = p[7];
    bReg[0] = cvt8(b0, b1); bReg[1] = cvt8(b2, b3);
    bReg[2] = cvt8(b4, b5); bReg[3] = cvt8(b6, b7);
  };

  f32x4 acc[4][4];
  #pragma unroll
  for (int i = 0; i < 4; i++)
    #pragma unroll
    for (int j = 0; j < 4; j++) acc[i][j] = (f32x4){0.f, 0.f, 0.f, 0.f};

  loadA(0); loadB(0);

  for (int k0 = 0; k0 < IN_; k0 += 64) {
    __syncthreads();
    #pragma unroll
    for (int j = 0; j < 4; j++) *(uint4*)&As[sr][sc + j * 8] = aReg[j];
    #pragma unroll
    for (int j = 0; j < 4; j++) *(short8*)&Bs[sr][sc + j * 8] = bReg[j];
    __syncthreads();
    if (k0 + 64 < IN_) { loadA(k0 + 64); loadB(k0 + 64); }

    #pragma unroll
    for (int kc = 0; kc < 2; kc++) {
      short8 af[4], bf[4];
      #pragma unroll
      for (int mi = 0; mi < 4; mi++)
        af[mi] = *(const short8*)&As[wm * 64 + mi * 16 + l16][kc * 32 + quad * 8];
      #pragma unroll
      for (int ni = 0; ni < 4; ni++)
        bf[ni] = *(const short8*)&Bs[wn * 64 + ni * 16 + l16][kc * 32 + quad * 8];
      #pragma unroll
      for (int mi = 0; mi < 4; mi++)
        #pragma unroll
        for (int ni = 0; ni < 4; ni++)
          acc[mi][ni] = __builtin_amdgcn_mfma_f32_16x16x32_bf16(af[mi], bf[ni], acc[mi][ni], 0, 0, 0);
    }
  }

  // epilogue: C/D layout col=l16, row=quad*4+reg
  #pragma unroll
  for (int mi = 0; mi < 4; mi++) {
    const int t = t0 + wm * 64 + mi * 16 + quad * 4;
    const int bb = t >> 11, nn = t & (N_ - 1);
    #pragma unroll
    for (int ni = 0; ni < 4; ni++) {
      const int c = c0 + wn * 64 + ni * 16 + l16;
      const int cc = c >> 9, cw = c & 511;
      const int hh = cw >> 6, dd = cw & 63;
      if (cc == 2) {
        ushort4 pk;
        pk.x = f2bf(acc[mi][ni][0]); pk.y = f2bf(acc[mi][ni][1]);
        pk.z = f2bf(acc[mi][ni][2]); pk.w = f2bf(acc[mi][ni][3]);
        *(ushort4*)(vws + ((size_t)(bb * H_ + hh) * D_ + dd) * N_ + nn) = pk;
      } else {
        unsigned short* dst = (cc == 0) ? qws : kws;
        size_t base = ((size_t)(bb * H_ + hh) * N_ + nn) * D_ + dd;
        dst[base]          = f2bf(acc[mi][ni][0]);
        dst[base + D_]     = f2bf(acc[mi][ni][1]);
        dst[base + 2 * D_] = f2bf(acc[mi][ni][2]);
        dst[base + 3 * D_] = f2bf(acc[mi][ni][3]);
      }
    }
  }
}

// ---------------------------------------------------------------------------
// Kernel 2: flash attention, transposed-S scheme.
// S^T = K·Q^T via mfma_16x16x32 (A=K frag, B=Q frag); softmax stats per-lane
// (query = l16, 2-step butterfly over quads); P^T feeds PV directly from
// registers as B operand of mfma_16x16x16bf16_1k (O^T = V^T·P^T).
// No P LDS round-trip; 2 barriers/iter; K/V staging prefetched.
// ---------------------------------------------------------------------------
__global__ __launch_bounds__(256) void attention_kernel(
    const unsigned short* __restrict__ qws,
    const unsigned short* __restrict__ kws,
    const unsigned short* __restrict__ vws,
    unsigned short* __restrict__ ows)
{
  __shared__ __attribute__((aligned(16))) unsigned short Ks[64][72];
  __shared__ __attribute__((aligned(16))) unsigned short Vs[64][72];

  const int q0 = blockIdx.x * 128;
  const int bh = blockIdx.y;
  const int tid = threadIdx.x;
  const int wave = tid >> 6, lane = tid & 63;
  const int quad = lane >> 4, l16 = lane & 15;

  const unsigned short* qbase = qws + (size_t)bh * N_ * D_;
  const unsigned short* kbase = kws + (size_t)bh * N_ * D_;
  const unsigned short* vbase = vws + (size_t)bh * D_ * N_;

  // Q fragments direct from global: B-layout [col=query=l16][k=d=quad*8+j]
  short8 qf[2][2];
  #pragma unroll
  for (int mb = 0; mb < 2; mb++)
    #pragma unroll
    for (int kc = 0; kc < 2; kc++)
      qf[mb][kc] = *(const short8*)(qbase +
          (size_t)(q0 + wave * 32 + mb * 16 + l16) * D_ + kc * 32 + quad * 8);

  f32x4 ot[4][2];   // O^T accum: [db][mb], row=d=quad*4+reg, col=query=l16
  float mi[2], li[2];
  #pragma unroll
  for (int db = 0; db < 4; db++)
    #pragma unroll
    for (int mb = 0; mb < 2; mb++) ot[db][mb] = (f32x4){0.f, 0.f, 0.f, 0.f};
  mi[0] = mi[1] = -1e30f; li[0] = li[1] = 0.f;

  // staging: K tile 64x64, V^T tile 64x64; 4 thr/row, 16 shorts each
  const int sr = tid >> 2, sc = (tid & 3) * 16;
  uint4 kreg[2], vreg[2];
  auto load_tile = [&](int k0) {
    const uint4* kp = (const uint4*)(kbase + (size_t)(k0 + sr) * D_ + sc);
    kreg[0] = kp[0]; kreg[1] = kp[1];
    const uint4* vp = (const uint4*)(vbase + (size_t)sr * N_ + k0 + sc);
    vreg[0] = vp[0]; vreg[1] = vp[1];
  };
  load_tile(0);

  for (int kt = 0; kt < N_ / 64; kt++) {
    __syncthreads();
    *(uint4*)&Ks[sr][sc]     = kreg[0];
    *(uint4*)&Ks[sr][sc + 8] = kreg[1];
    *(uint4*)&Vs[sr][sc]     = vreg[0];
    *(uint4*)&Vs[sr][sc + 8] = vreg[1];
    __syncthreads();
    if (kt + 1 < N_ / 64) load_tile((kt + 1) * 64);

    // --- S^T = K·Q^T : st[mb][nb], rows = keys nb*16+quad*4+r, col = query l16
    f32x4 st[2][4];
    #pragma unroll
    for (int mb = 0; mb < 2; mb++)
      #pragma unroll
      for (int nb = 0; nb < 4; nb++) st[mb][nb] = (f32x4){0.f, 0.f, 0.f, 0.f};
    #pragma unroll
    for (int kc = 0; kc < 2; kc++) {
      short8 kf[4];
      #pragma unroll
      for (int nb = 0; nb < 4; nb++)
        kf[nb] = *(const short8*)&Ks[nb * 16 + l16][kc * 32 + quad * 8];
      #pragma unroll
      for (int mb = 0; mb < 2; mb++)
        #pragma unroll
        for (int nb = 0; nb < 4; nb++)
          st[mb][nb] = __builtin_amdgcn_mfma_f32_16x16x32_bf16(kf[nb], qf[mb][kc], st[mb][nb], 0, 0, 0);
    }

    // --- online softmax (exp2 domain), P^T packed to B-operand frags ---
    bs4 pf[2][4];
    #pragma unroll
    for (int mb = 0; mb < 2; mb++) {
      float rmax = st[mb][0][0];
      #pragma unroll
      for (int nb = 0; nb < 4; nb++)
        #pragma unroll
        for (int r = 0; r < 4; r++) rmax = fmaxf(rmax, st[mb][nb][r]);
      rmax = fmaxf(rmax, __shfl_xor(rmax, 16));
      rmax = fmaxf(rmax, __shfl_xor(rmax, 32));
      const float mnew = fmaxf(mi[mb], rmax * CLOG2_);
      const float alpha = __builtin_amdgcn_exp2f(mi[mb] - mnew);
      mi[mb] = mnew;
      float rsum = 0.f;
      #pragma unroll
      for (int nb = 0; nb < 4; nb++) {
        bs4 p4;
        #pragma unroll
        for (int r = 0; r < 4; r++) {
          float p = __builtin_amdgcn_exp2f(fmaf(st[mb][nb][r], CLOG2_, -mnew));
          rsum += p;
          p4[r] = (short)f2bf(p);
        }
        pf[mb][nb] = p4;
      }
      rsum += __shfl_xor(rsum, 16);
      rsum += __shfl_xor(rsum, 32);
      li[mb] = li[mb] * alpha + rsum;
      #pragma unroll
      for (int db = 0; db < 4; db++)
        #pragma unroll
        for (int r = 0; r < 4; r++) ot[db][mb][r] *= alpha;
    }

    // --- O^T += V^T · P^T : A = V^T frag from LDS, B = pf from registers ---
    #pragma unroll
    for (int kb = 0; kb < 4; kb++) {
      bs4 vf[4];
      #pragma unroll
      for (int db = 0; db < 4; db++)
        vf[db] = *(const bs4*)&Vs[db * 16 + l16][kb * 16 + quad * 4];
      #pragma unroll
      for (int db = 0; db < 4; db++)
        #pragma unroll
        for (int mb = 0; mb < 2; mb++)
          ot[db][mb] = __builtin_amdgcn_mfma_f32_16x16x16bf16_1k(vf[db], pf[mb][kb], ot[db][mb], 0, 0, 0);
    }
  }

  // --- epilogue: O^T/l -> bf16 -> ows[b][n][h*64+d] ---
  const int b_ = bh >> 3, h_ = bh & 7;
  #pragma unroll
  for (int mb = 0; mb < 2; mb++) {
    const float inv = 1.f / li[mb];
    const int qrow = q0 + wave * 32 + mb * 16 + l16;
    #pragma unroll
    for (int db = 0; db < 4; db++) {
      ushort4 pk;
      pk.x = f2bf(ot[db][mb][0] * inv);
      pk.y = f2bf(ot[db][mb][1] * inv);
      pk.z = f2bf(ot[db][mb][2] * inv);
      pk.w = f2bf(ot[db][mb][3] * inv);
      *(ushort4*)(ows + ((size_t)b_ * N_ + qrow) * (H_ * D_) + h_ * 64 + db * 16 + quad * 4) = pk;
    }
  }
}

// ---------------------------------------------------------------------------
// Kernel 3: output projection. y[t][c] = sum_o A[t][o]*Wo[c][o] + bo[c].
// Same 128x128 / BK=64 structure; A bf16 (attention out), B fp32 Wo.
// ---------------------------------------------------------------------------
__global__ __launch_bounds__(256, 3) void out_gemm_kernel(
    const unsigned short* __restrict__ ain, const float* __restrict__ Wo,
    const float* __restrict__ bo, float* __restrict__ y)
{
  __shared__ __attribute__((aligned(16))) unsigned short As[128][72];
  __shared__ __attribute__((aligned(16))) unsigned short Bs[128][72];

  const int t0 = blockIdx.x * 128;
  const int c0 = blockIdx.y * 128;
  const int tid = threadIdx.x;
  const int wave = tid >> 6, lane = tid & 63;
  const int quad = lane >> 4, l16 = lane & 15;
  const int wm = wave >> 1, wn = wave & 1;
  const int sr = tid >> 1, sc = (tid & 1) * 32;

  uint4 aReg[4];
  short8 bReg[4];
  auto loadA = [&](int k0) {
    const uint4* p = (const uint4*)(ain + (size_t)(t0 + sr) * IN_ + k0 + sc);
    aReg[0] = p[0]; aReg[1] = p[1]; aReg[2] = p[2]; aReg[3] = p[3];
  };
  auto loadB = [&](int k0) {
    const float4* p = (const float4*)(Wo + (size_t)(c0 + sr) * IN_ + k0 + sc);
    float4 b0 = p[0], b1 = p[1], b2 = p[2], b3 = p[3];
    float4 b4 = p[4], b5 = p[5], b6 = p[6], b7 = p[7];
    bReg[0] = cvt8(b0, b1); bReg[1] = cvt8(b2, b3);
    bReg[2] = cvt8(b4, b5); bReg[3] = cvt8(b6, b7);
  };

  f32x4 acc[4][4];
  #pragma unroll
  for (int i = 0; i < 4; i++)
    #pragma unroll
    for (int j = 0; j < 4; j++) acc[i][j] = (f32x4){0.f, 0.f, 0.f, 0.f};

  loadA(0); loadB(0);

  for (int k0 = 0; k0 < IN_; k0 += 64) {
    __syncthreads();
    #pragma unroll
    for (int j = 0; j < 4; j++) *(uint4*)&As[sr][sc + j * 8] = aReg[j];
    #pragma unroll
    for (int j = 0; j < 4; j++) *(short8*)&Bs[sr][sc + j * 8] = bReg[j];
    __syncthreads();
    if (k0 + 64 < IN_) { loadA(k0 + 64); loadB(k0 + 64); }

    #pragma unroll
    for (int kc = 0; kc < 2; kc++) {
      short8 af[4], bf[4];
      #pragma unroll
      for (int mi = 0; mi < 4; mi++)
        af[mi] = *(const short8*)&As[wm * 64 + mi * 16 + l16][kc * 32 + quad * 8];
      #pragma unroll
      for (int ni = 0; ni < 4; ni++)
        bf[ni] = *(const short8*)&Bs[wn * 64 + ni * 16 + l16][kc * 32 + quad * 8];
      #pragma unroll
      for (int mi = 0; mi < 4; mi++)
        #pragma unroll
        for (int ni = 0; ni < 4; ni++)
          acc[mi][ni] = __builtin_amdgcn_mfma_f32_16x16x32_bf16(af[mi], bf[ni], acc[mi][ni], 0, 0, 0);
    }
  }

  #pragma unroll
  for (int mi = 0; mi < 4; mi++) {
    const int t = t0 + wm * 64 + mi * 16 + quad * 4;
    #pragma unroll
    for (int ni = 0; ni < 4; ni++) {
      const int c = c0 + wn * 64 + ni * 16 + l16;
      const float bias = bo[c];
      float* dst = y + (size_t)t * IN_ + c;
      dst[0]        = acc[mi][ni][0] + bias;
      dst[IN_]      = acc[mi][ni][1] + bias;
      dst[2 * IN_]  = acc[mi][ni][2] + bias;
      dst[3 * IN_]  = acc[mi][ni][3] + bias;
    }
  }
}

extern "C" void kernel_launch(void* const* d_in, const int* in_sizes, int n_in,
                              void* d_out, int out_size, void* d_ws, size_t ws_size,
                              hipStream_t stream) {
  const float* x   = (const float*)d_in[0];
  const float* Wq  = (const float*)d_in[1];
  const float* Wkv = (const float*)d_in[2];
  const float* Wo  = (const float*)d_in[3];
  const float* bo  = (const float*)d_in[4];
  float* out = (float*)d_out;

  // ws: q 8MB | k 8MB | v 8MB | ows 8MB (ows doubles as x_bf before attention)
  unsigned short* qws = (unsigned short*)d_ws;
  unsigned short* kws = qws + (size_t)TOK_ * 512;
  unsigned short* vws = kws + (size_t)TOK_ * 512;
  unsigned short* ows = vws + (size_t)TOK_ * 512;
  unsigned short* xbf = ows;  // alias: x_bf consumed by qkv_gemm before attention writes ows

  conv_x_kernel<<<dim3(TOK_ * IN_ / (256 * 8)), 256, 0, stream>>>(x, xbf);
  qkv_gemm_kernel<<<dim3(TOK_ / 128, 1536 / 128), 256, 0, stream>>>(xbf, Wq, Wkv, qws, kws, vws);
  attention_kernel<<<dim3(N_ / 128, B_ * H_), 256, 0, stream>>>(qws, kws, vws, ows);
  out_gemm_kernel<<<dim3(TOK_ / 128, 512 / 128), 256, 0, stream>>>(ows, Wo, bo, out);
}